// Round 8
// baseline (265.453 us; speedup 1.0000x reference)
//
#include <hip/hip_runtime.h>

typedef __bf16 bf16x8 __attribute__((ext_vector_type(8)));
typedef float f32x4 __attribute__((ext_vector_type(4)));
typedef float fl4 __attribute__((ext_vector_type(4)));
typedef unsigned short us4 __attribute__((ext_vector_type(4)));
typedef unsigned short us8 __attribute__((ext_vector_type(8)));

__device__ __forceinline__ unsigned short f2bf(float f) {
  unsigned u = __builtin_bit_cast(unsigned, f);
  u += 0x7fffu + ((u >> 16) & 1u);
  return (unsigned short)(u >> 16);
}
__device__ __forceinline__ float bf2f(unsigned short h) {
  unsigned u = ((unsigned)h) << 16;
  return __builtin_bit_cast(float, u);
}

__device__ __forceinline__ void async16(const void* g, void* l) {
  __builtin_amdgcn_global_load_lds(
      (const __attribute__((address_space(1))) unsigned int*)g,
      (__attribute__((address_space(3))) unsigned int*)l, 16, 0, 0);
}

#define BARM() asm volatile("s_barrier" ::: "memory")
#define VMCNT4() asm volatile("s_waitcnt vmcnt(4)" ::: "memory")
#define LGKM0() asm volatile("s_waitcnt lgkmcnt(0)" ::: "memory")
#define LGKM8() asm volatile("s_waitcnt lgkmcnt(8)" ::: "memory")
#define SCHEDB() __builtin_amdgcn_sched_barrier(0)

// ---------------- fp32 -> bf16 convert (x and W merged) ----------------
__global__ __launch_bounds__(256) void cvt_bf16_2(const float* __restrict__ sA,
                                                  unsigned short* __restrict__ dA, int nA,
                                                  const float* __restrict__ sB,
                                                  unsigned short* __restrict__ dB, int nB) {
  int i = blockIdx.x * 256 + threadIdx.x;
  const float* s;
  unsigned short* d;
  if (i < nA) {
    s = sA; d = dA;
  } else {
    i -= nA;
    if (i >= nB) return;
    s = sB; d = dB;
  }
  fl4 f = ((const fl4*)s)[i];
  us4 o;
  o[0] = f2bf(f[0]); o[1] = f2bf(f[1]); o[2] = f2bf(f[2]); o[3] = f2bf(f[3]);
  ((us4*)d)[i] = o;
}

// ---------------- transpose v: vT[b][c][t] = kqv[b*2048+t][2048+c] ----------------
__global__ __launch_bounds__(256) void transpose_v(const unsigned short* __restrict__ kqv,
                                                   unsigned short* __restrict__ vT) {
  int b = blockIdx.z;
  int t0 = blockIdx.x * 64;
  int c0 = blockIdx.y * 64;
  __shared__ unsigned short tile[64][68];
  int tid = threadIdx.x;
#pragma unroll
  for (int i = 0; i < 4; ++i) {
    int idx = i * 256 + tid;
    int r = idx >> 4;
    int c4 = (idx & 15) * 4;
    const unsigned short* src = kqv + ((size_t)(b * 2048 + t0 + r)) * 3072 + 2048 + c0 + c4;
    us4 v = *(const us4*)src;
    *(us4*)&tile[r][c4] = v;
  }
  __syncthreads();
#pragma unroll
  for (int i = 0; i < 4; ++i) {
    int idx = i * 256 + tid;
    int rc = idx >> 4;
    int t4 = (idx & 15) * 4;
    us4 v;
    v[0] = tile[t4 + 0][rc]; v[1] = tile[t4 + 1][rc];
    v[2] = tile[t4 + 2][rc]; v[3] = tile[t4 + 3][rc];
    unsigned short* dst = vT + ((size_t)(b * 1024 + c0 + rc)) * 2048 + t0 + t4;
    *(us4*)dst = v;
  }
}

// ---------------- 256x256 8-phase bf16 MFMA GEMM -------------------------------
// r6 schedule; swizzle changed to st_16x32 (m201): 32B-granule XOR
// c ^= ((row>>2)&1)<<5 applied to BOTH the DMA global source and ds_read addr.
template <int EPI>
__global__ __launch_bounds__(512, 2) void gemm8p(
    const unsigned short* __restrict__ A, int lda, long long sA,
    const unsigned short* __restrict__ B, int ldb, long long sB,
    void* __restrict__ Cv, int ldc, long long sC,
    const float* __restrict__ bias, float scale, int K, int NBX) {
  int bx, by;
  const int bz = blockIdx.z;
  if (EPI == 0) {
    int flat = blockIdx.x;
    int q = (int)gridDim.x >> 3;
    int swz = (flat & 7) * q + (flat >> 3);
    bx = swz % NBX; by = swz / NBX;
  } else {
    bx = blockIdx.x; by = blockIdx.y;
    if (EPI == 1 && bx > by) return;
  }
  A += (size_t)bz * sA;
  B += (size_t)bz * sB;
  const int rowBase = by * 256;
  const int colBase = bx * 256;
  const int nk = K / 64;

  __shared__ __align__(16) unsigned char lds[131072];
  const int tid = threadIdx.x;
  const int lane = tid & 63;
  const int wid = tid >> 6;
  const int wr = wid >> 2;
  const int wc = wid & 3;
  const int l15 = lane & 15, l4 = lane >> 4;

  f32x4 acc[8][4] = {};
  bf16x8 af0[4][2], af1[4][2], bf0[2][2], bf1[2][2];

  const unsigned short* Ab = A + (size_t)rowBase * lda;
  const unsigned short* Bb = B + (size_t)colBase * ldb;
  unsigned loff[2][2];
  unsigned lldso[2];
#pragma unroll
  for (int i = 0; i < 2; ++i) {
    int off = (i * 512 + tid) * 16;
    int r = off >> 7;
    int c = off & 127;
    int cs = c ^ (((r >> 2) & 1) << 5);   // st_16x32 inverse on source
    lldso[i] = (unsigned)off;
#pragma unroll
    for (int h = 0; h < 2; ++h)
      loff[h][i] = (unsigned)((h * 128 + r) * lda + (cs >> 1));
  }

  auto STAGE = [&](int bufc, int isB, int half, const unsigned short* Gb, int koff) {
#pragma unroll
    for (int i = 0; i < 2; ++i)
      async16(Gb + (size_t)(loff[half][i] + (unsigned)koff),
              lds + bufc * 65536 + isB * 32768 + half * 16384 + lldso[i]);
  };
  auto RDA = [&](int bufc, int m, int kk) -> bf16x8 {
    int row = m * 16 + l15;
    int cs = ((kk * 4 + l4) * 16) ^ (((row >> 2) & 1) << 5);
    return *(const bf16x8*)(lds + bufc * 65536 + wr * 16384 + row * 128 + cs);
  };
  auto RDB = [&](int bufc, int n, int kk) -> bf16x8 {
    int row = (wc & 1) * 64 + n * 16 + l15;
    int cs = ((kk * 4 + l4) * 16) ^ (((row >> 2) & 1) << 5);
    return *(const bf16x8*)(lds + bufc * 65536 + 32768 + (wc >> 1) * 16384 +
                            row * 128 + cs);
  };

#define RDA8(dst, BUF, Q)                                                      \
  _Pragma("unroll") for (int mi = 0; mi < 4; ++mi)                             \
  _Pragma("unroll") for (int kk = 0; kk < 2; ++kk)                             \
      dst[mi][kk] = RDA((BUF), (Q) * 4 + mi, kk)
#define RDB4(dst, BUF, NB)                                                     \
  _Pragma("unroll") for (int nj = 0; nj < 2; ++nj)                             \
  _Pragma("unroll") for (int kk = 0; kk < 2; ++kk)                             \
      dst[nj][kk] = RDB((BUF), (NB) + nj, kk)

#define MFMAQ(MB, NB, AF, BF)                                                  \
  _Pragma("unroll") for (int kk = 0; kk < 2; ++kk)                             \
  _Pragma("unroll") for (int mi = 0; mi < 4; ++mi)                             \
  _Pragma("unroll") for (int nj = 0; nj < 2; ++nj)                             \
      acc[(MB) + mi][(NB) + nj] = __builtin_amdgcn_mfma_f32_16x16x32_bf16(     \
          AF[mi][kk], BF[nj][kk], acc[(MB) + mi][(NB) + nj], 0, 0, 0)

#define PH(RDS, STG, HINT, GATE, MB, NB, AF, BF)                               \
  do {                                                                         \
    RDS;                                                                       \
    STG;                                                                       \
    HINT;                                                                      \
    BARM();                                                                    \
    LGKM0();                                                                   \
    SCHEDB();                                                                  \
    __builtin_amdgcn_s_setprio(1);                                             \
    MFMAQ(MB, NB, AF, BF);                                                     \
    __builtin_amdgcn_s_setprio(0);                                             \
    GATE;                                                                      \
    BARM();                                                                    \
  } while (0)

  STAGE(0, 0, 0, Ab, 0);
  STAGE(0, 0, 1, Ab, 0);
  STAGE(0, 1, 0, Bb, 0);
  STAGE(0, 1, 1, Bb, 0);
  STAGE(1, 1, 0, Bb, 64);
  STAGE(1, 1, 1, Bb, 64);
  VMCNT4();
  BARM();

  const int nt2 = nk >> 1;
  for (int it = 0; it < nt2; ++it) {
    int t = it * 2;
    int kA1 = (t + 1) * 64;
    int k2 = (t + 2 < nk - 1 ? t + 2 : nk - 1) * 64;
    int k3 = (t + 3 < nk - 1 ? t + 3 : nk - 1) * 64;
    PH({ RDA8(af0, 0, 0); RDB4(bf0, 0, 0); }, STAGE(1, 0, 0, Ab, kA1), LGKM8(),
       (void)0, 0, 0, af0, bf0);
    PH({ RDB4(bf1, 0, 2); }, STAGE(1, 0, 1, Ab, kA1), (void)0,
       (void)0, 0, 2, af0, bf1);
    PH({ RDA8(af1, 0, 1); }, STAGE(0, 1, 0, Bb, k2), (void)0,
       (void)0, 4, 2, af1, bf1);
    PH({}, STAGE(0, 1, 1, Bb, k2), (void)0,
       VMCNT4(), 4, 0, af1, bf0);
    PH({ RDA8(af0, 1, 0); RDB4(bf0, 1, 0); }, STAGE(0, 0, 0, Ab, k2), LGKM8(),
       (void)0, 0, 0, af0, bf0);
    PH({ RDB4(bf1, 1, 2); }, STAGE(0, 0, 1, Ab, k2), (void)0,
       (void)0, 0, 2, af0, bf1);
    PH({ RDA8(af1, 1, 1); }, STAGE(1, 1, 0, Bb, k3), (void)0,
       (void)0, 4, 2, af1, bf1);
    PH({}, STAGE(1, 1, 1, Bb, k3), (void)0,
       VMCNT4(), 4, 0, af1, bf0);
  }
#undef PH
#undef MFMAQ
#undef RDA8
#undef RDB4

  const int cr = l4 * 4;
  if constexpr (EPI == 0) {
    unsigned short* C = (unsigned short*)Cv;
#pragma unroll
    for (int n = 0; n < 4; ++n) {
      int col = colBase + wc * 64 + n * 16 + l15;
      float bv = bias[col];
#pragma unroll
      for (int m = 0; m < 8; ++m) {
        int row = rowBase + wr * 128 + m * 16 + cr;
#pragma unroll
        for (int i = 0; i < 4; ++i)
          C[(size_t)(row + i) * ldc + col] = f2bf(acc[m][n][i] + bv);
      }
    }
  } else {
    unsigned short* C = (unsigned short*)Cv + (size_t)bz * sC;
#pragma unroll
    for (int n = 0; n < 4; ++n) {
      int col = colBase + wc * 64 + n * 16 + l15;
#pragma unroll
      for (int m = 0; m < 8; ++m) {
        int row = rowBase + wr * 128 + m * 16 + cr;
#pragma unroll
        for (int i = 0; i < 4; ++i)
          C[(size_t)(row + i) * ldc + col] = f2bf(acc[m][n][i] * scale);
      }
    }
  }
}

// ---------------- fused flash PV: out = softmax_causal(S) @ vT^T --------------
// Tile 128 rows x 128 cols, 4 waves (4M x 1N): wave owns 32 rows, all cols.
// Per K-step (BK=32 of s): stage S-tile (A) + vT-tile (B); S-frags read in
// A-layout (row=l&15, k=(l>>4)*8+j — proven by the working GEMM) become P-frags
// via elementwise exp2(s-m) with online max/sum; causal mask s<=t elementwise.
// Row stats lane-local (shfl over l4); one same-wave LDS bounce moves the
// rescale factor to C-row space. Epilogue divides by l. Heavy rows first.
__global__ __launch_bounds__(256, 2) void flash_pv(
    const unsigned short* __restrict__ S, const unsigned short* __restrict__ V,
    float* __restrict__ O) {
  const int bx = blockIdx.x;
  const int by = (int)gridDim.y - 1 - blockIdx.y;  // heavy (large-K) first
  const int bz = blockIdx.z;
  const unsigned short* Sb = S + (size_t)bz * 2048 * 2048;
  const unsigned short* Vb = V + (size_t)bz * 1024 * 2048;
  float* Ob = O + (size_t)bz * 2048 * 1024;
  const int rowBase = by * 128, colBase = bx * 128;
  const int nk = (rowBase + 128) / 32;

  __shared__ __align__(16) unsigned char lds[16896];  // S 8KB | V 8KB | stats 512B
  float* scr = (float*)(lds + 16384);
  const int tid = threadIdx.x;
  const int lane = tid & 63, wid = tid >> 6;
  const int l15 = lane & 15, l4 = lane >> 4;
  const int awrow = wid * 32;

  f32x4 acc[2][8] = {};
  float mrun[2] = {-3.0e38f, -3.0e38f};
  float lrun[2] = {0.f, 0.f};

  for (int kt = 0; kt < nk; ++kt) {
    const int kof = kt * 32;
    __syncthreads();
#pragma unroll
    for (int i = 0; i < 2; ++i) {
      int off = (i * 256 + tid) * 16;
      int r = off >> 6;
      int gblk = ((off >> 4) & 3) ^ ((r >> 1) & 3);
      async16(Sb + (size_t)(rowBase + r) * 2048 + kof + gblk * 8, lds + off);
      async16(Vb + (size_t)(colBase + r) * 2048 + kof + gblk * 8, lds + 8192 + off);
    }
    __syncthreads();
    if (kof <= rowBase + awrow + 31) {   // wave-uniform: any valid row?
      bf16x8 bfr[8];
#pragma unroll
      for (int n = 0; n < 8; ++n) {
        int row = n * 16 + l15;
        bfr[n] = *(const bf16x8*)(lds + 8192 + row * 64 + (((l4 ^ (row >> 1)) & 3) * 16));
      }
      bf16x8 pa[2];
#pragma unroll
      for (int m = 0; m < 2; ++m) {
        int row = awrow + m * 16 + l15;
        us8 sraw = *(const us8*)(lds + row * 64 + (((l4 ^ (row >> 1)) & 3) * 16));
        const int trow = rowBase + row;
        const int sbase = kof + l4 * 8;
        float sv[8];
        float vmax = -3.0e38f;
#pragma unroll
        for (int j = 0; j < 8; ++j) {
          sv[j] = bf2f(sraw[j]);
          if (sbase + j <= trow) vmax = fmaxf(vmax, sv[j]);
        }
        vmax = fmaxf(vmax, __shfl_xor(vmax, 16, 64));
        vmax = fmaxf(vmax, __shfl_xor(vmax, 32, 64));
        float mnew = fmaxf(mrun[m], vmax);
        float sc = exp2f(mrun[m] - mnew);
        mrun[m] = mnew;
        float rs = 0.f;
        us8 pk;
#pragma unroll
        for (int j = 0; j < 8; ++j) {
          float p = (sbase + j <= trow) ? exp2f(sv[j] - mnew) : 0.f;
          rs += p;
          pk[j] = f2bf(p);
        }
        rs += __shfl_xor(rs, 16, 64);
        rs += __shfl_xor(rs, 32, 64);
        lrun[m] = lrun[m] * sc + rs;
        pa[m] = __builtin_bit_cast(bf16x8, pk);
        if (l4 == 0) scr[awrow + m * 16 + l15] = sc;   // same-wave publish
      }
#pragma unroll
      for (int m = 0; m < 2; ++m) {
#pragma unroll
        for (int i = 0; i < 4; ++i) {
          float s = scr[awrow + m * 16 + l4 * 4 + i];   // C-row rescale
#pragma unroll
          for (int n = 0; n < 8; ++n) acc[m][n][i] *= s;
        }
#pragma unroll
        for (int n = 0; n < 8; ++n)
          acc[m][n] = __builtin_amdgcn_mfma_f32_16x16x32_bf16(pa[m], bfr[n], acc[m][n], 0, 0, 0);
      }
    }
  }
#pragma unroll
  for (int m = 0; m < 2; ++m)
    if (l4 == 0) scr[awrow + m * 16 + l15] = 1.0f / lrun[m];
#pragma unroll
  for (int m = 0; m < 2; ++m) {
#pragma unroll
    for (int i = 0; i < 4; ++i) {
      float linv = scr[awrow + m * 16 + l4 * 4 + i];
      int row = rowBase + awrow + m * 16 + l4 * 4 + i;
#pragma unroll
      for (int n = 0; n < 8; ++n)
        Ob[(size_t)row * 1024 + colBase + n * 16 + l15] = acc[m][n][i] * linv;
    }
  }
}

extern "C" void kernel_launch(void* const* d_in, const int* in_sizes, int n_in,
                              void* d_out, int out_size, void* d_ws, size_t ws_size,
                              hipStream_t stream) {
  const float* x = (const float*)d_in[0];      // [4,2048,1024]
  const float* W = (const float*)d_in[1];      // [3072,1024]
  const float* bias = (const float*)d_in[2];   // [3072]
  float* out = (float*)d_out;                  // [4,2048,1024]

  char* ws = (char*)d_ws;
  // layout: xbf 16MB (aliased by vT after gemm0) | wbf 6MB | kqv 48MB | S 32MB
  if (ws_size < 106954752u) return;
  unsigned short* xbf = (unsigned short*)(ws);
  unsigned short* vT = xbf;  // alias: xbf dead after gemm8p<0>
  unsigned short* wbf = (unsigned short*)(ws + 16777216);
  unsigned short* kqv = (unsigned short*)(ws + 23068672);
  unsigned short* S = (unsigned short*)(ws + 73400320);

  const float kSoftmaxScale = 1.4426950408889634f / 32.0f;  // log2(e)/sqrt(1024)

  cvt_bf16_2<<<11264, 256, 0, stream>>>(x, xbf, 2097152, W, wbf, 786432);

  // kqv = x @ W^T + b (M=8192, N=3072, K=1024); grid 32x12 = 384, XCD swizzle
  gemm8p<0><<<dim3(384, 1, 1), 512, 0, stream>>>(
      xbf, 1024, 0LL, wbf, 1024, 0LL, kqv, 3072, 0LL, bias, 1.0f, 1024, 12);

  transpose_v<<<dim3(32, 16, 4), 256, 0, stream>>>(kqv, vT);

  // S = (k @ q^T) * log2e/32 (bf16 raw scores), causal blocks skipped
  gemm8p<1><<<dim3(8, 8, 4), 512, 0, stream>>>(
      kqv, 3072, 2048LL * 3072, kqv + 1024, 3072, 2048LL * 3072,
      S, 2048, 2048LL * 2048, nullptr, kSoftmaxScale, 1024, 0);

  // out = softmax_causal(S) @ vT^T, fused flash-style (no softmax kernel)
  flash_pv<<<dim3(8, 16, 4), 256, 0, stream>>>(S, vT, out);
}

// Round 9
// 184.567 us; speedup vs baseline: 1.4383x; 1.4383x over previous
//
#include <hip/hip_runtime.h>

typedef __bf16 bf16x8 __attribute__((ext_vector_type(8)));
typedef float f32x4 __attribute__((ext_vector_type(4)));
typedef float fl4 __attribute__((ext_vector_type(4)));
typedef unsigned short us4 __attribute__((ext_vector_type(4)));
typedef unsigned short us8 __attribute__((ext_vector_type(8)));

__device__ __forceinline__ unsigned short f2bf(float f) {
  unsigned u = __builtin_bit_cast(unsigned, f);
  u += 0x7fffu + ((u >> 16) & 1u);
  return (unsigned short)(u >> 16);
}
__device__ __forceinline__ float bf2f(unsigned short h) {
  unsigned u = ((unsigned)h) << 16;
  return __builtin_bit_cast(float, u);
}

__device__ __forceinline__ void async16(const void* g, void* l) {
  __builtin_amdgcn_global_load_lds(
      (const __attribute__((address_space(1))) unsigned int*)g,
      (__attribute__((address_space(3))) unsigned int*)l, 16, 0, 0);
}

#define BARM() asm volatile("s_barrier" ::: "memory")
#define VMCNT4() asm volatile("s_waitcnt vmcnt(4)" ::: "memory")
#define VMCNT6() asm volatile("s_waitcnt vmcnt(6)" ::: "memory")
#define LGKM0() asm volatile("s_waitcnt lgkmcnt(0)" ::: "memory")
#define LGKM8() asm volatile("s_waitcnt lgkmcnt(8)" ::: "memory")
#define SCHEDB() __builtin_amdgcn_sched_barrier(0)

// ---------------- fp32 -> bf16 convert (x and W merged) ----------------
__global__ __launch_bounds__(256) void cvt_bf16_2(const float* __restrict__ sA,
                                                  unsigned short* __restrict__ dA, int nA,
                                                  const float* __restrict__ sB,
                                                  unsigned short* __restrict__ dB, int nB) {
  int i = blockIdx.x * 256 + threadIdx.x;
  const float* s;
  unsigned short* d;
  if (i < nA) {
    s = sA; d = dA;
  } else {
    i -= nA;
    if (i >= nB) return;
    s = sB; d = dB;
  }
  fl4 f = ((const fl4*)s)[i];
  us4 o;
  o[0] = f2bf(f[0]); o[1] = f2bf(f[1]); o[2] = f2bf(f[2]); o[3] = f2bf(f[3]);
  ((us4*)d)[i] = o;
}

// ---------------- transpose v: vT[b][c][t] = kqv[b*2048+t][2048+c] ----------------
__global__ __launch_bounds__(256) void transpose_v(const unsigned short* __restrict__ kqv,
                                                   unsigned short* __restrict__ vT) {
  int b = blockIdx.z;
  int t0 = blockIdx.x * 64;
  int c0 = blockIdx.y * 64;
  __shared__ unsigned short tile[64][68];
  int tid = threadIdx.x;
#pragma unroll
  for (int i = 0; i < 4; ++i) {
    int idx = i * 256 + tid;
    int r = idx >> 4;
    int c4 = (idx & 15) * 4;
    const unsigned short* src = kqv + ((size_t)(b * 2048 + t0 + r)) * 3072 + 2048 + c0 + c4;
    us4 v = *(const us4*)src;
    *(us4*)&tile[r][c4] = v;
  }
  __syncthreads();
#pragma unroll
  for (int i = 0; i < 4; ++i) {
    int idx = i * 256 + tid;
    int rc = idx >> 4;
    int t4 = (idx & 15) * 4;
    us4 v;
    v[0] = tile[t4 + 0][rc]; v[1] = tile[t4 + 1][rc];
    v[2] = tile[t4 + 2][rc]; v[3] = tile[t4 + 3][rc];
    unsigned short* dst = vT + ((size_t)(b * 1024 + c0 + rc)) * 2048 + t0 + t4;
    *(us4*)dst = v;
  }
}

// ---------------- g0: 128x384 8-phase GEMM, 512 blocks = 2 exact rounds -------
// kqv = x @ W^T + bias. 8 waves (2M x 4N): wave = 64 rows x 96 cols (4x6 frags).
// LDS 128KB: 2 bufs x (A 16KB | B 48KB). A-tile = 2 DMA ops, B-tile = 6.
// Per iteration (tiles t->buf0, t+1->buf1), 16 ops, 2 K-tiles:
//  ph1: rd A01+B012 (10), stg A(t+1)->buf1 (2)  ; mfma m01 x n012
//  ph2: rd A23+B345 (10)                        ; mfma m01 x n345
//  ph3: stg B(t+2)->buf0 op0-2                  ; mfma m23 x n345
//  ph4: stg B(t+2)->buf0 op3-5 ; GATE vmcnt(6)  ; mfma m23 x n012
//  ph5-8: mirror on buf1; stg A(t+2)->buf0 @ph5, B(t+3)->buf1 @ph7/8; GATE ph8.
// B-writes start >=1 phase after that buffer's last B-read drains (r6-proven).
__global__ __launch_bounds__(512, 2) void gemm_g0(
    const unsigned short* __restrict__ A, const unsigned short* __restrict__ B,
    unsigned short* __restrict__ C, const float* __restrict__ bias) {
  const int flat = blockIdx.x;
  const int swz = (flat & 7) * 64 + (flat >> 3);   // XCD-contiguous remap
  const int bx = swz & 7;
  const int by = swz >> 3;
  const int rowBase = by * 128, colBase = bx * 384;
  const int lda = 1024, ldc = 3072, nk = 16;

  __shared__ __align__(16) unsigned char lds[131072];
  const int tid = threadIdx.x;
  const int lane = tid & 63, wid = tid >> 6;
  const int wr = wid >> 2, wc = wid & 3;
  const int l15 = lane & 15, l4 = lane >> 4, l7 = lane & 7;

  f32x4 acc[4][6] = {};
  bf16x8 af01[2][2], af23[2][2], bf[6][2];

  const unsigned short* Ab = A + (size_t)rowBase * lda;
  const unsigned short* Bb = B + (size_t)colBase * lda;
  unsigned aoff[2], boff[6], aldso[2], bldso[6];
#pragma unroll
  for (int i = 0; i < 6; ++i) {
    int off = i * 8192 + tid * 16;
    int r = off >> 7;
    int sb = ((off >> 4) & 7) ^ (r & 7);
    if (i < 2) { aoff[i] = (unsigned)(r * lda + sb * 8); aldso[i] = (unsigned)off; }
    boff[i] = (unsigned)(r * lda + sb * 8);
    bldso[i] = (unsigned)off;
  }

  auto STA = [&](int bufc, int op, int koff) {
    async16(Ab + (size_t)(aoff[op] + (unsigned)koff), lds + bufc * 65536 + aldso[op]);
  };
  auto STB = [&](int bufc, int op, int koff) {
    async16(Bb + (size_t)(boff[op] + (unsigned)koff),
            lds + bufc * 65536 + 16384 + bldso[op]);
  };
  auto RA = [&](int bufc, int m, int kk) -> bf16x8 {
    int row = wr * 64 + m * 16 + l15;
    int blk = (kk * 4 + l4) ^ l7;
    return *(const bf16x8*)(lds + bufc * 65536 + row * 128 + blk * 16);
  };
  auto RB = [&](int bufc, int n, int kk) -> bf16x8 {
    int row = wc * 96 + n * 16 + l15;
    int blk = (kk * 4 + l4) ^ l7;
    return *(const bf16x8*)(lds + bufc * 65536 + 16384 + row * 128 + blk * 16);
  };

#define RD_A01(BUF)                                                            \
  _Pragma("unroll") for (int mi = 0; mi < 2; ++mi)                             \
  _Pragma("unroll") for (int kk = 0; kk < 2; ++kk) af01[mi][kk] = RA((BUF), mi, kk)
#define RD_A23(BUF)                                                            \
  _Pragma("unroll") for (int mi = 0; mi < 2; ++mi)                             \
  _Pragma("unroll") for (int kk = 0; kk < 2; ++kk) af23[mi][kk] = RA((BUF), 2 + mi, kk)
#define RD_B(BUF, N0)                                                          \
  _Pragma("unroll") for (int nj = 0; nj < 3; ++nj)                             \
  _Pragma("unroll") for (int kk = 0; kk < 2; ++kk) bf[(N0) + nj][kk] = RB((BUF), (N0) + nj, kk)

#define MQ(MB, NB, AF)                                                         \
  _Pragma("unroll") for (int kk = 0; kk < 2; ++kk)                             \
  _Pragma("unroll") for (int mi = 0; mi < 2; ++mi)                             \
  _Pragma("unroll") for (int nj = 0; nj < 3; ++nj)                             \
      acc[(MB) + mi][(NB) + nj] = __builtin_amdgcn_mfma_f32_16x16x32_bf16(     \
          AF[mi][kk], bf[(NB) + nj][kk], acc[(MB) + mi][(NB) + nj], 0, 0, 0)

#define PHASE(RDS, STG, GATE, MB, NB, AF)                                      \
  do {                                                                         \
    RDS;                                                                       \
    STG;                                                                       \
    BARM();                                                                    \
    LGKM0();                                                                   \
    SCHEDB();                                                                  \
    __builtin_amdgcn_s_setprio(1);                                             \
    MQ(MB, NB, AF);                                                            \
    __builtin_amdgcn_s_setprio(0);                                             \
    GATE;                                                                      \
    BARM();                                                                    \
  } while (0)

  // prologue: A(0),B(0)->buf0, B(1)->buf1 ; gate leaves B(1)'s 6 ops in flight
  STA(0, 0, 0); STA(0, 1, 0);
#pragma unroll
  for (int i = 0; i < 6; ++i) STB(0, i, 0);
#pragma unroll
  for (int i = 0; i < 6; ++i) STB(1, i, 64);
  VMCNT6();
  BARM();

  for (int it = 0; it < 8; ++it) {
    int t = it * 2;
    int kA1 = (t + 1) * 64;
    int k2 = (t + 2 < nk - 1 ? t + 2 : nk - 1) * 64;
    int k3 = (t + 3 < nk - 1 ? t + 3 : nk - 1) * 64;
    // tile t from buf0
    PHASE({ RD_A01(0); RD_B(0, 0); }, { STA(1, 0, kA1); STA(1, 1, kA1); },
          (void)0, 0, 0, af01);
    PHASE({ RD_A23(0); RD_B(0, 3); }, (void)0, (void)0, 0, 3, af01);
    PHASE({}, { STB(0, 0, k2); STB(0, 1, k2); STB(0, 2, k2); },
          (void)0, 2, 3, af23);
    PHASE({}, { STB(0, 3, k2); STB(0, 4, k2); STB(0, 5, k2); },
          VMCNT6(), 2, 0, af23);
    // tile t+1 from buf1
    PHASE({ RD_A01(1); RD_B(1, 0); }, { STA(0, 0, k2); STA(0, 1, k2); },
          (void)0, 0, 0, af01);
    PHASE({ RD_A23(1); RD_B(1, 3); }, (void)0, (void)0, 0, 3, af01);
    PHASE({}, { STB(1, 0, k3); STB(1, 1, k3); STB(1, 2, k3); },
          (void)0, 2, 3, af23);
    PHASE({}, { STB(1, 3, k3); STB(1, 4, k3); STB(1, 5, k3); },
          VMCNT6(), 2, 0, af23);
  }
#undef PHASE
#undef MQ
#undef RD_A01
#undef RD_A23
#undef RD_B

  const int cr = l4 * 4;
#pragma unroll
  for (int n = 0; n < 6; ++n) {
    int col = colBase + wc * 96 + n * 16 + l15;
    float bv = bias[col];
#pragma unroll
    for (int m = 0; m < 4; ++m) {
      int row = rowBase + wr * 64 + m * 16 + cr;
#pragma unroll
      for (int i = 0; i < 4; ++i)
        C[(size_t)(row + i) * ldc + col] = f2bf(acc[m][n][i] + bv);
    }
  }
}

// ---------------- 256x256 8-phase bf16 MFMA GEMM (r6 verbatim; g1/g2) ---------
template <int EPI>
__global__ __launch_bounds__(512, 2) void gemm8p(
    const unsigned short* __restrict__ A, int lda, long long sA,
    const unsigned short* __restrict__ B, int ldb, long long sB,
    void* __restrict__ Cv, int ldc, long long sC,
    float scale, int K) {
  int bx = blockIdx.x, by = blockIdx.y;
  const int bz = blockIdx.z;
  if (EPI == 1 && bx > by) return;
  A += (size_t)bz * sA;
  B += (size_t)bz * sB;
  const int rowBase = by * 256;
  const int colBase = bx * 256;
  const int nk = (EPI == 2) ? (rowBase + 256) / 64 : K / 64;

  __shared__ __align__(16) unsigned char lds[131072];
  const int tid = threadIdx.x;
  const int lane = tid & 63;
  const int wid = tid >> 6;
  const int wr = wid >> 2;
  const int wc = wid & 3;
  const int l15 = lane & 15, l4 = lane >> 4, l7 = lane & 7;

  f32x4 acc[8][4] = {};
  bf16x8 af0[4][2], af1[4][2], bf0[2][2], bf1[2][2];

  const unsigned short* Ab = A + (size_t)rowBase * lda;
  const unsigned short* Bb = B + (size_t)colBase * ldb;
  unsigned loff[2][2];
  unsigned lldso[2];
#pragma unroll
  for (int i = 0; i < 2; ++i) {
    int off = (i * 512 + tid) * 16;
    int r = off >> 7;
    int sb = ((off >> 4) & 7) ^ (r & 7);
    lldso[i] = (unsigned)off;
#pragma unroll
    for (int h = 0; h < 2; ++h)
      loff[h][i] = (unsigned)((h * 128 + r) * lda + sb * 8);
  }

  auto STAGE = [&](int bufc, int isB, int half, const unsigned short* Gb, int koff) {
#pragma unroll
    for (int i = 0; i < 2; ++i)
      async16(Gb + (size_t)(loff[half][i] + (unsigned)koff),
              lds + bufc * 65536 + isB * 32768 + half * 16384 + lldso[i]);
  };
  auto RDA = [&](int bufc, int m, int kk) -> bf16x8 {
    int row = m * 16 + l15;
    int blk = (kk * 4 + l4) ^ l7;
    return *(const bf16x8*)(lds + bufc * 65536 + wr * 16384 + row * 128 + blk * 16);
  };
  auto RDB = [&](int bufc, int n, int kk) -> bf16x8 {
    int row = (wc & 1) * 64 + n * 16 + l15;
    int blk = (kk * 4 + l4) ^ l7;
    return *(const bf16x8*)(lds + bufc * 65536 + 32768 + (wc >> 1) * 16384 +
                            row * 128 + blk * 16);
  };

#define RDA8(dst, BUF, Q)                                                      \
  _Pragma("unroll") for (int mi = 0; mi < 4; ++mi)                             \
  _Pragma("unroll") for (int kk = 0; kk < 2; ++kk)                             \
      dst[mi][kk] = RDA((BUF), (Q) * 4 + mi, kk)
#define RDB4(dst, BUF, NB)                                                     \
  _Pragma("unroll") for (int nj = 0; nj < 2; ++nj)                             \
  _Pragma("unroll") for (int kk = 0; kk < 2; ++kk)                             \
      dst[nj][kk] = RDB((BUF), (NB) + nj, kk)

#define MFMAQ(MB, NB, AF, BF)                                                  \
  _Pragma("unroll") for (int kk = 0; kk < 2; ++kk)                             \
  _Pragma("unroll") for (int mi = 0; mi < 4; ++mi)                             \
  _Pragma("unroll") for (int nj = 0; nj < 2; ++nj)                             \
      acc[(MB) + mi][(NB) + nj] = __builtin_amdgcn_mfma_f32_16x16x32_bf16(     \
          AF[mi][kk], BF[nj][kk], acc[(MB) + mi][(NB) + nj], 0, 0, 0)

#define PH(RDS, STG, HINT, GATE, MB, NB, AF, BF)                               \
  do {                                                                         \
    RDS;                                                                       \
    STG;                                                                       \
    HINT;                                                                      \
    BARM();                                                                    \
    LGKM0();                                                                   \
    SCHEDB();                                                                  \
    __builtin_amdgcn_s_setprio(1);                                             \
    MFMAQ(MB, NB, AF, BF);                                                     \
    __builtin_amdgcn_s_setprio(0);                                             \
    GATE;                                                                      \
    BARM();                                                                    \
  } while (0)

  STAGE(0, 0, 0, Ab, 0);
  STAGE(0, 0, 1, Ab, 0);
  STAGE(0, 1, 0, Bb, 0);
  STAGE(0, 1, 1, Bb, 0);
  {
    int k1 = ((1 < nk - 1) ? 1 : (nk - 1)) * 64;
    STAGE(1, 1, 0, Bb, k1);
    STAGE(1, 1, 1, Bb, k1);
  }
  VMCNT4();
  BARM();

  const int nt2 = nk >> 1;
  for (int it = 0; it < nt2; ++it) {
    int t = it * 2;
    int kA1 = (t + 1) * 64;
    int k2 = (t + 2 < nk - 1 ? t + 2 : nk - 1) * 64;
    int k3 = (t + 3 < nk - 1 ? t + 3 : nk - 1) * 64;
    PH({ RDA8(af0, 0, 0); RDB4(bf0, 0, 0); }, STAGE(1, 0, 0, Ab, kA1), LGKM8(),
       (void)0, 0, 0, af0, bf0);
    PH({ RDB4(bf1, 0, 2); }, STAGE(1, 0, 1, Ab, kA1), (void)0,
       (void)0, 0, 2, af0, bf1);
    PH({ RDA8(af1, 0, 1); }, STAGE(0, 1, 0, Bb, k2), (void)0,
       (void)0, 4, 2, af1, bf1);
    PH({}, STAGE(0, 1, 1, Bb, k2), (void)0,
       VMCNT4(), 4, 0, af1, bf0);
    PH({ RDA8(af0, 1, 0); RDB4(bf0, 1, 0); }, STAGE(0, 0, 0, Ab, k2), LGKM8(),
       (void)0, 0, 0, af0, bf0);
    PH({ RDB4(bf1, 1, 2); }, STAGE(0, 0, 1, Ab, k2), (void)0,
       (void)0, 0, 2, af0, bf1);
    PH({ RDA8(af1, 1, 1); }, STAGE(1, 1, 0, Bb, k3), (void)0,
       (void)0, 4, 2, af1, bf1);
    PH({}, STAGE(1, 1, 1, Bb, k3), (void)0,
       VMCNT4(), 4, 0, af1, bf0);
  }
#undef PH
#undef MFMAQ
#undef RDA8
#undef RDB4

  const int cr = l4 * 4;
  if constexpr (EPI == 1) {
    unsigned short* C = (unsigned short*)Cv + (size_t)bz * sC;
#pragma unroll
    for (int n = 0; n < 4; ++n) {
      int col = colBase + wc * 64 + n * 16 + l15;
#pragma unroll
      for (int m = 0; m < 8; ++m) {
        int row = rowBase + wr * 128 + m * 16 + cr;
#pragma unroll
        for (int i = 0; i < 4; ++i)
          C[(size_t)(row + i) * ldc + col] = f2bf(acc[m][n][i] * scale);
      }
    }
  } else {
    float* C = (float*)Cv + (size_t)bz * sC;
#pragma unroll
    for (int n = 0; n < 4; ++n) {
      int col = colBase + wc * 64 + n * 16 + l15;
#pragma unroll
      for (int m = 0; m < 8; ++m) {
        int row = rowBase + wr * 128 + m * 16 + cr;
#pragma unroll
        for (int i = 0; i < 4; ++i)
          C[(size_t)(row + i) * ldc + col] = acc[m][n][i];
      }
    }
  }
}

// ---------------- causal softmax over S rows (in place, bf16) ----------------
__global__ __launch_bounds__(256) void softmax_causal(unsigned short* __restrict__ S) {
  const int T = 2048;
  int t = blockIdx.x, b = blockIdx.y;
  unsigned short* row = S + ((size_t)b * T + t) * T;
  const int nv = t + 1;
  const int bound = ((t >> 8) + 1) << 8;
  int tid = threadIdx.x;
  int lane = tid & 63, wid = tid >> 6;
  int s0 = tid * 8;
  us8 raw = {};
  if (s0 < nv) raw = *(const us8*)(row + s0);
  float v[8];
  float m = -3.0e38f;
#pragma unroll
  for (int j = 0; j < 8; ++j) {
    v[j] = bf2f(raw[j]);
    if (s0 + j < nv) m = fmaxf(m, v[j]);
  }
#pragma unroll
  for (int o = 32; o > 0; o >>= 1) m = fmaxf(m, __shfl_xor(m, o, 64));
  __shared__ float red[4];
  if (lane == 0) red[wid] = m;
  __syncthreads();
  m = fmaxf(fmaxf(red[0], red[1]), fmaxf(red[2], red[3]));
  __syncthreads();
  float sum = 0.f;
#pragma unroll
  for (int j = 0; j < 8; ++j) {
    float e = (s0 + j < nv) ? exp2f(v[j] - m) : 0.f;
    v[j] = e;
    sum += e;
  }
#pragma unroll
  for (int o = 32; o > 0; o >>= 1) sum += __shfl_xor(sum, o, 64);
  if (lane == 0) red[wid] = sum;
  __syncthreads();
  sum = red[0] + red[1] + red[2] + red[3];
  float inv = 1.0f / sum;
  if (s0 < bound) {
    us8 outv;
#pragma unroll
    for (int j = 0; j < 8; ++j) outv[j] = f2bf(v[j] * inv);
    *(us8*)(row + s0) = outv;
  }
}

extern "C" void kernel_launch(void* const* d_in, const int* in_sizes, int n_in,
                              void* d_out, int out_size, void* d_ws, size_t ws_size,
                              hipStream_t stream) {
  const float* x = (const float*)d_in[0];      // [4,2048,1024]
  const float* W = (const float*)d_in[1];      // [3072,1024]
  const float* bias = (const float*)d_in[2];   // [3072]
  float* out = (float*)d_out;                  // [4,2048,1024]

  char* ws = (char*)d_ws;
  if (ws_size < 106954752u) return;
  unsigned short* xbf = (unsigned short*)(ws);
  unsigned short* vT = xbf;  // alias: xbf dead after gemm_g0
  unsigned short* wbf = (unsigned short*)(ws + 16777216);
  unsigned short* kqv = (unsigned short*)(ws + 23068672);
  unsigned short* S = (unsigned short*)(ws + 73400320);

  const float kSoftmaxScale = 1.4426950408889634f / 32.0f;  // log2(e)/sqrt(1024)

  cvt_bf16_2<<<11264, 256, 0, stream>>>(x, xbf, 2097152, W, wbf, 786432);

  // kqv = x @ W^T + b : 128x384 tiles, 8x64 = 512 blocks = 2 exact rounds
  gemm_g0<<<dim3(512, 1, 1), 512, 0, stream>>>(xbf, wbf, kqv, bias);

  transpose_v<<<dim3(32, 16, 4), 256, 0, stream>>>(kqv, vT);

  // S = (k @ q^T) * log2e/32 (bf16), causal blocks skipped
  gemm8p<1><<<dim3(8, 8, 4), 512, 0, stream>>>(
      kqv, 3072, 2048LL * 3072, kqv + 1024, 3072, 2048LL * 3072,
      S, 2048, 2048LL * 2048, kSoftmaxScale, 1024);

  softmax_causal<<<dim3(2048, 4), 256, 0, stream>>>(S);

  // out = P @ vT^T (fp32), K truncated at diagonal
  gemm8p<2><<<dim3(4, 8, 4), 512, 0, stream>>>(
      S, 2048, 2048LL * 2048, vT, 2048, 1024LL * 2048,
      out, 1024, 2048LL * 1024, 1.0f, 2048);
}